// Round 5
// baseline (95.227 us; speedup 1.0000x reference)
//
#include <hip/hip_runtime.h>
#include <math.h>

#define BB 8192
#define DD 4096
#define EE 64

constexpr float NOISE_EPS = 0.01f;
constexpr int BM = 16;              // rows per block
constexpr int BK = 32;              // K per stage (one MFMA K)
constexpr int NT = DD / BK;         // 128
constexpr int WR = 128;             // weight rows (64 gw + 64 ngw)

typedef __attribute__((ext_vector_type(8))) _Float16 f16x8;
typedef __attribute__((ext_vector_type(2))) _Float16 f16x2;
typedef __attribute__((ext_vector_type(4))) float    f32x4;

// ---------- pre-pass: split weights into fp16 hi/mid planes in ws ----------
// ws layout: [plane 0=hi,1=mid][row 0..127][k 0..4095] fp16 ; rows 64.. = ngw
__global__ __launch_bounds__(256) void wsplit_kernel(
    const float* __restrict__ gw, const float* __restrict__ ngw,
    _Float16* __restrict__ ws)
{
    const int gid = blockIdx.x * 256 + threadIdx.x;   // pair id, 262144 total
    const int row = gid >> 11;                        // 0..127
    const int k   = (gid & 2047) * 2;
    const float* src = (row < EE) ? gw + (size_t)row * DD + k
                                  : ngw + (size_t)(row - EE) * DD + k;
    float2 v = *reinterpret_cast<const float2*>(src);
    _Float16 h0 = (_Float16)v.x, h1 = (_Float16)v.y;      // RN
    f16x2 hi = {h0, h1};
    f16x2 mi = {(_Float16)(v.x - (float)h0), (_Float16)(v.y - (float)h1)};
    *reinterpret_cast<f16x2*>(ws + (size_t)row * DD + k) = hi;
    *reinterpret_cast<f16x2*>(ws + (size_t)WR * DD + (size_t)row * DD + k) = mi;
}

// ---------------------------- main fused kernel ----------------------------
template <bool PRESPLIT>
__global__ __launch_bounds__(512, 4) void gating_kernel(
    const float* __restrict__ x,      // [B, D]
    const float* __restrict__ gw,     // [E, D]  (fallback only)
    const float* __restrict__ ngw,    // [E, D]  (fallback only)
    const _Float16* __restrict__ wsp, // [2][128][4096] fp16 (presplit)
    const float* __restrict__ noise,  // [B, E]
    float* __restrict__ out)          // gates [B,E] then load [B,E]
{
    __shared__ __align__(16) _Float16 xpl[2][2][BM * BK];   //  4 KB
    __shared__ __align__(16) _Float16 wpl[2][2][WR * BK];   // 32 KB
    __shared__ float lg[BM][132];                           // ~8.4 KB

    const int tid  = threadIdx.x;
    const int row0 = blockIdx.x * BM;
    const int lane = tid & 63;
    const int wv   = tid >> 6;          // 0..7 : wave owns cols [16wv,16wv+16)
    const int l15  = lane & 15;
    const int kq   = lane >> 4;

    // fragment offsets (halfword index)
    const int aoff = l15 * BK + kq * 8;
    const int boff = (wv * 16 + l15) * BK + kq * 8;

    // ---- x staging: threads 0..255, 2 floats each (16x32 tile) ----
    const int xr = (tid & 255) >> 4;        // 0..15
    const int xc = (tid & 15) * 2;          // 0..30
    const float* xp = x + (size_t)(row0 + xr) * DD + xc;
    const int xso = xr * BK + xc;

    // ---- w staging (presplit): thread -> (plane, row, 16-half chunk) ----
    const int pw   = tid >> 8;              // 0..1
    const int wrow = (tid >> 1) & 127;      // 0..127
    const int whf  = tid & 1;               // 0..1
    const _Float16* wqp = wsp + (size_t)pw * (WR * DD) + (size_t)wrow * DD + whf * 16;
    const int wso_p = pw * (WR * BK) + wrow * BK + whf * 16;

    // ---- w staging (fallback): thread -> (row, 8 floats) ----
    const int frow = tid >> 2;              // 0..127
    const int fqc  = (tid & 3) * 8;         // 0,8,16,24
    const float* fwp = ((frow < EE) ? gw + (size_t)frow * DD
                                    : ngw + (size_t)(frow - EE) * DD) + fqc;
    const int wso_f = frow * BK + fqc;

    f32x4 acc = {0.f, 0.f, 0.f, 0.f};

    f16x8 wa0, wa1, wb0, wb1;               // presplit pipeline regs
    float4 fa0, fa1, fb0, fb1;              // fallback pipeline regs
    float2 xa = {0.f, 0.f}, xb = {0.f, 0.f};

    auto LOADW = [&](int t, f16x8& u0, f16x8& u1, float4& g0, float4& g1) {
        if constexpr (PRESPLIT) {
            u0 = *reinterpret_cast<const f16x8*>(wqp + (size_t)t * BK);
            u1 = *reinterpret_cast<const f16x8*>(wqp + (size_t)t * BK + 8);
        } else {
            g0 = *reinterpret_cast<const float4*>(fwp + (size_t)t * BK);
            g1 = *reinterpret_cast<const float4*>(fwp + (size_t)t * BK + 4);
        }
    };
    auto STOREW = [&](int b, const f16x8& u0, const f16x8& u1,
                      const float4& g0, const float4& g1) {
        if constexpr (PRESPLIT) {
            _Float16* base = &wpl[b][0][0];
            *reinterpret_cast<f16x8*>(base + wso_p)     = u0;
            *reinterpret_cast<f16x8*>(base + wso_p + 8) = u1;
        } else {
            float v[8] = {g0.x, g0.y, g0.z, g0.w, g1.x, g1.y, g1.z, g1.w};
            f16x8 hi, mi;
            #pragma unroll
            for (int j = 0; j < 8; ++j) {
                _Float16 h = (_Float16)v[j];
                hi[j] = h;
                mi[j] = (_Float16)(v[j] - (float)h);
            }
            *reinterpret_cast<f16x8*>(&wpl[b][0][wso_f]) = hi;
            *reinterpret_cast<f16x8*>(&wpl[b][1][wso_f]) = mi;
        }
    };
    auto STOREX = [&](int b, float2 v) {
        _Float16 h0 = (_Float16)v.x, h1 = (_Float16)v.y;
        f16x2 hi = {h0, h1};
        f16x2 mi = {(_Float16)(v.x - (float)h0), (_Float16)(v.y - (float)h1)};
        *reinterpret_cast<f16x2*>(&xpl[b][0][xso]) = hi;
        *reinterpret_cast<f16x2*>(&xpl[b][1][xso]) = mi;
    };

    // ---- prologue: tile 0 staged, tile 1 in regs ----
    LOADW(0, wa0, wa1, fa0, fa1);
    if (tid < 256) xa = *reinterpret_cast<const float2*>(xp);
    STOREW(0, wa0, wa1, fa0, fa1);
    if (tid < 256) STOREX(0, xa);
    LOADW(1, wa0, wa1, fa0, fa1);
    if (tid < 256) xa = *reinterpret_cast<const float2*>(xp + BK);
    __syncthreads();

    // ---- main loop: 1 barrier/iter, dist-2 register pipeline ----
    for (int t = 0; t < NT; ++t) {
        const int cur = t & 1, nxt = cur ^ 1;
        const bool more = (t + 2 < NT);

        if (more) {
            LOADW(t + 2, wb0, wb1, fb0, fb1);
            if (tid < 256) xb = *reinterpret_cast<const float2*>(xp + (size_t)(t + 2) * BK);
        }

        f16x8 ah = *reinterpret_cast<const f16x8*>(&xpl[cur][0][aoff]);
        f16x8 am = *reinterpret_cast<const f16x8*>(&xpl[cur][1][aoff]);
        f16x8 bh = *reinterpret_cast<const f16x8*>(&wpl[cur][0][boff]);
        f16x8 bm = *reinterpret_cast<const f16x8*>(&wpl[cur][1][boff]);
        acc = __builtin_amdgcn_mfma_f32_16x16x32_f16(ah, bh, acc, 0, 0, 0);
        acc = __builtin_amdgcn_mfma_f32_16x16x32_f16(am, bh, acc, 0, 0, 0);
        acc = __builtin_amdgcn_mfma_f32_16x16x32_f16(ah, bm, acc, 0, 0, 0);
        acc = __builtin_amdgcn_mfma_f32_16x16x32_f16(am, bm, acc, 0, 0, 0);

        if (t + 1 < NT) {
            STOREW(nxt, wa0, wa1, fa0, fa1);
            if (tid < 256) STOREX(nxt, xa);
        }
        if (more) { wa0 = wb0; wa1 = wb1; fa0 = fb0; fa1 = fb1; xa = xb; }
        __syncthreads();
    }

    // ---- accumulators -> logits tile ----
    {
        const int rb = kq * 4;
        const int c0 = wv * 16 + l15;
        #pragma unroll
        for (int j = 0; j < 4; ++j) lg[rb + j][c0] = acc[j];
    }
    __syncthreads();

    // ---- epilogue: 32 lanes per row, 2 experts per lane ----
    {
        const int r    = tid >> 5;           // 0..15
        const int sub  = tid & 31;
        const int e0   = sub * 2;
        const int grow = row0 + r;

        float2 nz = *reinterpret_cast<const float2*>(noise + (size_t)grow * EE + e0);
        float c0v = lg[r][e0],      c1v = lg[r][e0 + 1];
        float nl0 = lg[r][EE + e0], nl1 = lg[r][EE + e0 + 1];
        float sp0 = fmaxf(nl0, 0.f) + log1pf(expf(-fabsf(nl0)));
        float sp1 = fmaxf(nl1, 0.f) + log1pf(expf(-fabsf(nl1)));
        float v0  = fmaf(nz.x * sp0, NOISE_EPS, c0v);
        float v1  = fmaf(nz.y * sp1, NOISE_EPS, c1v);

        float m1, m2; int i1, i2;
        if (v1 > v0) { m1 = v1; i1 = e0 + 1; m2 = v0; i2 = e0; }
        else         { m1 = v0; i1 = e0;     m2 = v1; i2 = e0 + 1; }
        float cmax = fmaxf(c0v, c1v);

        #pragma unroll
        for (int m = 1; m < 32; m <<= 1) {
            float b1 = __shfl_xor(m1, m, 32);
            int  bi1 = __shfl_xor(i1, m, 32);
            float b2 = __shfl_xor(m2, m, 32);
            int  bi2 = __shfl_xor(i2, m, 32);
            cmax = fmaxf(cmax, __shfl_xor(cmax, m, 32));

            bool bwin = (b1 > m1) || (b1 == m1 && bi1 < i1);
            float t1; int ti1; float t2; int ti2;
            if (bwin) {
                t1 = b1; ti1 = bi1;
                bool aw = (m1 > b2) || (m1 == b2 && i1 < bi2);
                t2 = aw ? m1 : b2; ti2 = aw ? i1 : bi2;
            } else {
                t1 = m1; ti1 = i1;
                bool bw = (b1 > m2) || (b1 == m2 && bi1 < i2);
                t2 = bw ? b1 : m2; ti2 = bw ? bi1 : i2;
            }
            m1 = t1; i1 = ti1; m2 = t2; i2 = ti2;
        }

        float tq = expf(m2 - m1);
        float p1 = 1.0f / (1.0f + tq);
        float p2 = tq * p1;

        float eA = expf(c0v - cmax), eB = expf(c1v - cmax);
        float sum = eA + eB;
        #pragma unroll
        for (int m = 1; m < 32; m <<= 1) sum += __shfl_xor(sum, m, 32);
        float inv = 1.0f / sum;

        float2 gt = { (e0 == i1) ? p1 : (e0 == i2) ? p2 : 0.f,
                      (e0 + 1 == i1) ? p1 : (e0 + 1 == i2) ? p2 : 0.f };
        float2 ld = { eA * inv, eB * inv };
        *reinterpret_cast<float2*>(out + (size_t)grow * EE + e0) = gt;
        *reinterpret_cast<float2*>(out + (size_t)BB * EE + (size_t)grow * EE + e0) = ld;
    }
}

extern "C" void kernel_launch(void* const* d_in, const int* in_sizes, int n_in,
                              void* d_out, int out_size, void* d_ws, size_t ws_size,
                              hipStream_t stream) {
    const float* x     = (const float*)d_in[0];
    const float* gw    = (const float*)d_in[1];
    const float* ngw   = (const float*)d_in[2];
    const float* noise = (const float*)d_in[3];
    float* out = (float*)d_out;

    const size_t need = (size_t)2 * WR * DD * sizeof(_Float16);   // 2 MB
    if (ws_size >= need) {
        _Float16* ws = (_Float16*)d_ws;
        hipLaunchKernelGGL(wsplit_kernel, dim3(WR * DD / 2 / 256), dim3(256), 0, stream,
                           gw, ngw, ws);
        hipLaunchKernelGGL(gating_kernel<true>, dim3(BB / BM), dim3(512), 0, stream,
                           x, gw, ngw, ws, noise, out);
    } else {
        hipLaunchKernelGGL(gating_kernel<false>, dim3(BB / BM), dim3(512), 0, stream,
                           x, gw, ngw, (const _Float16*)d_ws, noise, out);
    }
}